// Round 1
// baseline (6732.030 us; speedup 1.0000x reference)
//
#include <hip/hip_runtime.h>
#include <cmath>

#define Bsz  4096
#define Tlen 512
#define Fnum 17
#define Hdim 32
#define Pnum 8
#define FPn  18
#define G3   96   // 3*Hdim

// ---------- fast math (≈1 ulp, plenty under 0.1775 absmax threshold) ----------
__device__ __forceinline__ float frcp(float x)  { return __builtin_amdgcn_rcpf(x); }
__device__ __forceinline__ float frsq(float x)  { return __builtin_amdgcn_rsqf(x); }
__device__ __forceinline__ float fsigmoid(float x) { return frcp(1.0f + __expf(-x)); }
__device__ __forceinline__ float ftanh(float x) {
    x = fminf(15.0f, fmaxf(-15.0f, x));          // avoid inf*0 = NaN at saturation
    float e = __expf(-2.0f * x);
    return (1.0f - e) * frcp(1.0f + e);
}

// ---------- prep: transpose W_hh[f][g][h] -> WT[f][h][g] (contiguous g for s_load) ----
__global__ void prep_w_kernel(const float* __restrict__ Whh, float* __restrict__ WT) {
    const int f = blockIdx.x;
    const int g = threadIdx.x;           // 0..95
    for (int k = 0; k < Hdim; ++k)
        WT[(size_t)f * Hdim * G3 + k * G3 + g] = Whh[(size_t)f * G3 * Hdim + g * Hdim + k];
}

// ---------- prep: prototype L2 norms ----------
__global__ void prep_pnorm_kernel(const float* __restrict__ protos, float* __restrict__ pnorm) {
    const int p    = threadIdx.x >> 5;   // 8 groups of 32 lanes
    const int lane = threadIdx.x & 31;
    float s = 0.0f;
    for (int j = lane; j < FPn * Hdim; j += 32) {
        float v = protos[p * FPn * Hdim + j];
        s = fmaf(v, v, s);
    }
    #pragma unroll
    for (int m = 16; m; m >>= 1) s += __shfl_xor(s, m);
    if (lane == 0) pnorm[p] = sqrtf(s);
}

// ---------- main GRU: 1 wave per (f, 64-b tile); lane = one b sequence ----------
// W streams via wave-uniform scalar loads (f is uniform per block).
__global__ __launch_bounds__(64, 1)
void gru_kernel(const float* __restrict__ x,    // [B,T,F]
                const float* __restrict__ Wih,  // [F,96]
                const float* __restrict__ bih,  // [F,96]
                const float* __restrict__ bhh,  // [F,96]
                const float* __restrict__ WT,   // [F,32,96]
                float* __restrict__ pre)        // [B,18,32], f<17 filled
{
    const int f = blockIdx.y;
    const int b = blockIdx.x * 64 + threadIdx.x;

    const float* __restrict__ wt = WT  + (size_t)f * Hdim * G3;
    const float* __restrict__ wi = Wih + (size_t)f * G3;
    const float* __restrict__ bi = bih + (size_t)f * G3;
    const float* __restrict__ bh = bhh + (size_t)f * G3;
    const float* __restrict__ xp = x   + (size_t)b * (Tlen * Fnum) + f;

    float h[Hdim];
    #pragma unroll
    for (int j = 0; j < Hdim; ++j) h[j] = 0.0f;

    for (int t = 0; t < Tlen; ++t) {
        const float xv = xp[(size_t)t * Fnum];   // issued early, used ~3000cy later

        float acc[G3];
        #pragma unroll
        for (int g = 0; g < G3; ++g) acc[g] = bh[g];

        #pragma unroll 4
        for (int k = 0; k < Hdim; ++k) {
            const float hv = h[k];
            const float* __restrict__ w = wt + k * G3;
            #pragma unroll
            for (int g = 0; g < G3; ++g) acc[g] = fmaf(w[g], hv, acc[g]);
        }

        #pragma unroll
        for (int j = 0; j < Hdim; ++j) {
            float r = fsigmoid(fmaf(xv, wi[j],          bi[j])          + acc[j]);
            float z = fsigmoid(fmaf(xv, wi[Hdim + j],   bi[Hdim + j])   + acc[Hdim + j]);
            float n = ftanh(fmaf(r, acc[2 * Hdim + j],
                             fmaf(xv, wi[2 * Hdim + j], bi[2 * Hdim + j])));
            h[j] = fmaf(z, h[j] - n, n);         // (1-z)*n + z*h
        }
    }

    float* __restrict__ o = pre + (size_t)b * (FPn * Hdim) + f * Hdim;
    #pragma unroll
    for (int j = 0; j < Hdim; ++j) o[j] = h[j];
}

// ---------- epilogue: 1 wave per b.  lane = (h = l&31, f-halfset = l>>5) --------
__global__ __launch_bounds__(64)
void post_kernel(const float* __restrict__ pre,     // [B,18,32] (f<17 valid)
                 const float* __restrict__ statics, // [B,4]
                 const float* __restrict__ demoW,   // [32,4]
                 const float* __restrict__ demob,   // [32]
                 const float* __restrict__ lnw,     // [18,32]
                 const float* __restrict__ lnb,     // [18,32]
                 const float* __restrict__ protos,  // [8,576]
                 const float* __restrict__ pnorm,   // [8]
                 const float* __restrict__ Wq,      // [32,8]
                 const float* __restrict__ bq,      // [32]
                 const float* __restrict__ Wk,      // [8,18]
                 const float* __restrict__ bk,      // [8]
                 const float* __restrict__ Wv,      // [8,18]
                 const float* __restrict__ bv,      // [8]
                 const float* __restrict__ outW,    // [32]
                 const float* __restrict__ outb,    // [1]
                 float* __restrict__ out_logits,    // [B]
                 float* __restrict__ out_dist,      // [B,8]
                 float* __restrict__ out_ht)        // [B,18,32]
{
    const int b     = blockIdx.x;
    const int l     = threadIdx.x;
    const int hl    = l & 31;
    const int fbase = (l >> 5) * 9;      // lanes 0-31: f 0..8 ; lanes 32-63: f 9..17

    // gather 9 values (f=17 slot = demo row computed in-register)
    float v[9];
    #pragma unroll
    for (int j = 0; j < 9; ++j) {
        const int fj = fbase + j;
        if (fj == 17) {
            float acc = demob[hl];
            #pragma unroll
            for (int d = 0; d < 4; ++d)
                acc = fmaf(statics[b * 4 + d], demoW[hl * 4 + d], acc);
            v[j] = acc;
        } else {
            v[j] = pre[(size_t)b * 576 + fj * 32 + hl];
        }
    }

    // LayerNorm over all 576
    float s = 0.0f, ss = 0.0f;
    #pragma unroll
    for (int j = 0; j < 9; ++j) { s += v[j]; ss = fmaf(v[j], v[j], ss); }
    #pragma unroll
    for (int m = 32; m; m >>= 1) { s += __shfl_xor(s, m); ss += __shfl_xor(ss, m); }
    const float mu  = s * (1.0f / 576.0f);
    const float var = ss * (1.0f / 576.0f) - mu * mu;
    const float rs  = frsq(var + 1e-5f);

    float nrm = 0.0f;
    #pragma unroll
    for (int j = 0; j < 9; ++j) {
        const int fj = fbase + j;
        float y = fmaf((v[j] - mu) * rs, lnw[fj * 32 + hl], lnb[fj * 32 + hl]);
        v[j] = y;
        out_ht[(size_t)b * 576 + fj * 32 + hl] = y;
        nrm = fmaf(y, y, nrm);
    }
    #pragma unroll
    for (int m = 32; m; m >>= 1) nrm += __shfl_xor(nrm, m);
    nrm = sqrtf(nrm);

    // cosine distances to 8 prototypes
    float dist[8];
    #pragma unroll
    for (int p = 0; p < Pnum; ++p) {
        float d = 0.0f;
        #pragma unroll
        for (int j = 0; j < 9; ++j)
            d = fmaf(v[j], protos[p * 576 + (fbase + j) * 32 + hl], d);
        #pragma unroll
        for (int m = 32; m; m >>= 1) d += __shfl_xor(d, m);
        dist[p] = d / fmaxf(nrm * pnorm[p], 1e-8f);
    }
    if (l == 0) {
        #pragma unroll
        for (int p = 0; p < Pnum; ++p) out_dist[(size_t)b * Pnum + p] = dist[p];
    }

    // q[h] = dist·Wq[h,:] + bq[h]   (replicated across the two half-waves)
    float q = bq[hl];
    #pragma unroll
    for (int p = 0; p < Pnum; ++p) q = fmaf(dist[p], Wq[hl * 8 + p], q);
    float Sq = q;
    #pragma unroll
    for (int m = 16; m; m >>= 1) Sq += __shfl_xor(Sq, m);   // sum_h q[h]

    // s[f] = sum_h hn[f,h] q[h] : reduce across the 32 lanes sharing f
    float sf[9], so[9];
    #pragma unroll
    for (int j = 0; j < 9; ++j) {
        float t = v[j] * q;
        #pragma unroll
        for (int m = 16; m; m >>= 1) t += __shfl_xor(t, m);
        sf[j] = t;
    }
    #pragma unroll
    for (int j = 0; j < 9; ++j) so[j] = __shfl_xor(sf[j], 32);  // other half's f-set
    const int obase = 9 - fbase;

    // e[p] = sum_f Wk[p,f] s[f] + bk[p]*Sq ; softmax over p
    float e[8];
    #pragma unroll
    for (int p = 0; p < Pnum; ++p) {
        float a = bk[p] * Sq;
        #pragma unroll
        for (int j = 0; j < 9; ++j) {
            a = fmaf(sf[j], Wk[p * FPn + fbase + j], a);
            a = fmaf(so[j], Wk[p * FPn + obase + j], a);
        }
        e[p] = a;
    }
    float mx = e[0];
    #pragma unroll
    for (int p = 1; p < Pnum; ++p) mx = fmaxf(mx, e[p]);
    float aw[8], den = 0.0f;
    #pragma unroll
    for (int p = 0; p < Pnum; ++p) { aw[p] = __expf(e[p] - mx); den += aw[p]; }
    const float rden = frcp(den);
    #pragma unroll
    for (int p = 0; p < Pnum; ++p) aw[p] *= rden;

    // v[b,h] = sum_f hn[f,h] * (sum_p a[p] Wv[p,f]) + sum_p a[p] bv[p]
    float c = 0.0f;
    #pragma unroll
    for (int p = 0; p < Pnum; ++p) c = fmaf(aw[p], bv[p], c);
    float vb = 0.0f;
    #pragma unroll
    for (int j = 0; j < 9; ++j) {
        float wv = 0.0f;
        #pragma unroll
        for (int p = 0; p < Pnum; ++p) wv = fmaf(aw[p], Wv[p * FPn + fbase + j], wv);
        vb = fmaf(v[j], wv, vb);
    }
    vb += __shfl_xor(vb, 32);     // add the other half's f-contributions
    vb += c;

    // logit = sigmoid(sum_h outW[h] * v[b,h] + outb)
    float lg = vb * outW[hl];
    #pragma unroll
    for (int m = 16; m; m >>= 1) lg += __shfl_xor(lg, m);
    lg = fsigmoid(lg + outb[0]);
    if (l == 0) out_logits[b] = lg;
}

extern "C" void kernel_launch(void* const* d_in, const int* in_sizes, int n_in,
                              void* d_out, int out_size, void* d_ws, size_t ws_size,
                              hipStream_t stream) {
    const float* x      = (const float*)d_in[0];
    const float* statics= (const float*)d_in[1];
    const float* Wih    = (const float*)d_in[2];
    const float* Whh    = (const float*)d_in[3];
    const float* bih    = (const float*)d_in[4];
    const float* bhh    = (const float*)d_in[5];
    const float* demoW  = (const float*)d_in[6];
    const float* demob  = (const float*)d_in[7];
    const float* lnw    = (const float*)d_in[8];
    const float* lnb    = (const float*)d_in[9];
    const float* protos = (const float*)d_in[10];
    const float* Wq     = (const float*)d_in[11];
    const float* bq     = (const float*)d_in[12];
    const float* Wk     = (const float*)d_in[13];
    const float* bk     = (const float*)d_in[14];
    const float* Wv     = (const float*)d_in[15];
    const float* bv     = (const float*)d_in[16];
    const float* outW   = (const float*)d_in[17];
    const float* outb   = (const float*)d_in[18];

    // workspace layout (~9.7 MB): pre[B*576] | WT[17*32*96] | pnorm[8]
    float* pre   = (float*)d_ws;
    float* WT    = pre + (size_t)Bsz * FPn * Hdim;
    float* pnorm = WT + (size_t)Fnum * Hdim * G3;

    prep_w_kernel<<<dim3(Fnum), dim3(G3), 0, stream>>>(Whh, WT);
    prep_pnorm_kernel<<<dim3(1), dim3(256), 0, stream>>>(protos, pnorm);

    gru_kernel<<<dim3(Bsz / 64, Fnum), dim3(64), 0, stream>>>(x, Wih, bih, bhh, WT, pre);

    float* out_logits = (float*)d_out;
    float* out_dist   = out_logits + Bsz;
    float* out_ht     = out_dist + (size_t)Bsz * Pnum;

    post_kernel<<<dim3(Bsz), dim3(64), 0, stream>>>(
        pre, statics, demoW, demob, lnw, lnb, protos, pnorm,
        Wq, bq, Wk, bk, Wv, bv, outW, outb,
        out_logits, out_dist, out_ht);
}

// Round 2
// 946.885 us; speedup vs baseline: 7.1097x; 7.1097x over previous
//
#include <hip/hip_runtime.h>
#include <cmath>

#define Bsz  4096
#define Tlen 512
#define Fnum 17
#define Hdim 32
#define Pnum 8
#define FPn  18
#define G3   96   // 3*Hdim

#define L2E   1.4426950408889634f
#define NL2E (-1.4426950408889634f)
#define TL2E  2.8853900817779268f   // 2*log2(e)

typedef __attribute__((ext_vector_type(8))) short short8v;
typedef __attribute__((ext_vector_type(4))) float float4v;

__device__ __forceinline__ float frcp(float x)  { return __builtin_amdgcn_rcpf(x); }
__device__ __forceinline__ float frsq(float x)  { return __builtin_amdgcn_rsqf(x); }
__device__ __forceinline__ float fexp2(float x) { return __builtin_amdgcn_exp2f(x); }
__device__ __forceinline__ float fsigmoid(float x) {
    return frcp(1.0f + fexp2(NL2E * x));
}
// RNE float->bf16 bits
__device__ __forceinline__ short bf16b(float x) {
    unsigned u = __float_as_uint(x);
    unsigned r = (u + 0x7FFFu + ((u >> 16) & 1u)) >> 16;
    return (short)r;
}
// packed f32x2 -> bf16x2 (hardware RNE)
__device__ __forceinline__ unsigned cvtpk(float lo, float hi) {
    unsigned r;
    asm("v_cvt_pk_bf16_f32 %0, %1, %2" : "=v"(r) : "v"(lo), "v"(hi));
    return r;
}

// ---------- prep: prototype L2 norms ----------
__global__ void prep_pnorm_kernel(const float* __restrict__ protos, float* __restrict__ pnorm) {
    const int p    = threadIdx.x >> 5;
    const int lane = threadIdx.x & 31;
    float s = 0.0f;
    for (int j = lane; j < FPn * Hdim; j += 32) {
        float v = protos[p * FPn * Hdim + j];
        s = fmaf(v, v, s);
    }
    #pragma unroll
    for (int m = 16; m; m >>= 1) s += __shfl_xor(s, m);
    if (lane == 0) pnorm[p] = sqrtf(s);
}

// ---------- prep: x[B,T,F] -> xT[F,T+1,B] in bf16 (t row 512 is scratch pad) ----
__global__ __launch_bounds__(64)
void xpose_kernel(const float* __restrict__ x, unsigned short* __restrict__ xT) {
    const int b = blockIdx.x * 64 + threadIdx.x;
    const int t = blockIdx.y;
    const float* __restrict__ xp = x + ((size_t)b * Tlen + t) * Fnum;
    #pragma unroll
    for (int ff = 0; ff < Fnum; ++ff)
        xT[(size_t)ff * (Tlen + 1) * Bsz + (size_t)t * Bsz + b] = (unsigned short)bf16b(xp[ff]);
}

// ---------- main GRU via MFMA -------------------------------------------------
// Block = 1 wave = (f, 16-b tile). Per step: hh' = Ws @ h^T via 6 MFMAs.
//   A-frag tile m (row rr=c, k=8S+i): Ws[pi(m,rr)][k],
//   pi(m,rr) = (m>>1)*32 + 8*(rr>>2) + (m&1)*4 + (rr&3)
// => lane (c,S) acc values are exactly gates r/z/n for j in {8S..8S+7} of b=B0+c,
//    which are exactly the B-frag slots (k=8S+i) it must supply next step.
// r,z rows of W/bias pre-scaled by -log2e; n rows by 2*log2e (exp2-form gates).
template<int USE_XT>
__global__ __launch_bounds__(64, 3)
void gru_mfma_kernel(const float* __restrict__ x,
                     const unsigned short* __restrict__ xT,
                     const float* __restrict__ Wih,   // [F,96]
                     const float* __restrict__ Whh,   // [F,96,32]
                     const float* __restrict__ bih,   // [F,96]
                     const float* __restrict__ bhh,   // [F,96]
                     float* __restrict__ pre)         // [B,18,32]
{
    const int f  = blockIdx.y;
    const int B0 = blockIdx.x * 16;
    const int l  = threadIdx.x;
    const int c  = l & 15, S = l >> 4;
    const int b  = B0 + c;

    const float* __restrict__ whh_f = Whh + (size_t)f * G3 * Hdim;
    const float* __restrict__ wih_f = Wih + (size_t)f * G3;
    const float* __restrict__ bih_f = bih + (size_t)f * G3;
    const float* __restrict__ bhh_f = bhh + (size_t)f * G3;

    // ---- one-time per-lane constants ----
    short8v afrag0, afrag1, afrag2, afrag3, afrag4, afrag5;
    float4v cinit0, cinit1, cinit2, cinit3, cinit4, cinit5;
    {
        union { short8v s; unsigned u[4]; } au;
        #pragma unroll
        for (int m = 0; m < 6; ++m) {
            const int gate = m >> 1;
            const float sc = (gate < 2) ? NL2E : TL2E;
            const int gA = gate * 32 + 8 * (c >> 2) + (m & 1) * 4 + (c & 3);
            const float* wrow = whh_f + (size_t)gA * Hdim + 8 * S;
            #pragma unroll
            for (int u = 0; u < 4; ++u)
                au.u[u] = cvtpk(wrow[2 * u] * sc, wrow[2 * u + 1] * sc);
            float4v ci;
            #pragma unroll
            for (int q = 0; q < 4; ++q) {
                const int gC = gate * 32 + 8 * S + (m & 1) * 4 + q;
                ci[q] = (gate < 2) ? NL2E * (bhh_f[gC] + bih_f[gC])
                                   : TL2E * bhh_f[gC];
            }
            if (m == 0) { afrag0 = au.s; cinit0 = ci; }
            if (m == 1) { afrag1 = au.s; cinit1 = ci; }
            if (m == 2) { afrag2 = au.s; cinit2 = ci; }
            if (m == 3) { afrag3 = au.s; cinit3 = ci; }
            if (m == 4) { afrag4 = au.s; cinit4 = ci; }
            if (m == 5) { afrag5 = au.s; cinit5 = ci; }
        }
    }
    float wr[8], wz[8], wn[8], bn[8];
    #pragma unroll
    for (int i = 0; i < 8; ++i) {
        const int j = 8 * S + i;
        wr[i] = NL2E * wih_f[j];
        wz[i] = NL2E * wih_f[32 + j];
        wn[i] = TL2E * wih_f[64 + j];
        bn[i] = TL2E * bih_f[64 + j];
    }

    float h[8];
    #pragma unroll
    for (int i = 0; i < 8; ++i) h[i] = 0.0f;

    // x addressing (prefetch one step ahead)
    const unsigned short* xtp = nullptr;
    const float* xp = nullptr;
    float xv_next;
    if (USE_XT) {
        xtp = xT + (size_t)f * (Tlen + 1) * Bsz + b;
        xv_next = __uint_as_float(((unsigned)*xtp) << 16);
    } else {
        xp = x + (size_t)b * Tlen * Fnum + f;
        xv_next = *xp;
    }

    for (int t = 0; t < Tlen; ++t) {
        const float xv = xv_next;
        if (USE_XT) {
            xtp += Bsz;                              // row T reads the scratch pad row
            xv_next = __uint_as_float(((unsigned)*xtp) << 16);
        } else {
            xp += (t < Tlen - 1) ? Fnum : 0;         // clamp: avoid OOB at t=511
            xv_next = *xp;
        }

        union { short8v s; unsigned u[4]; } bu;
        bu.u[0] = cvtpk(h[0], h[1]);
        bu.u[1] = cvtpk(h[2], h[3]);
        bu.u[2] = cvtpk(h[4], h[5]);
        bu.u[3] = cvtpk(h[6], h[7]);

        const float4v a0 = __builtin_amdgcn_mfma_f32_16x16x32_bf16(afrag0, bu.s, cinit0, 0, 0, 0);
        const float4v a1 = __builtin_amdgcn_mfma_f32_16x16x32_bf16(afrag1, bu.s, cinit1, 0, 0, 0);
        const float4v a2 = __builtin_amdgcn_mfma_f32_16x16x32_bf16(afrag2, bu.s, cinit2, 0, 0, 0);
        const float4v a3 = __builtin_amdgcn_mfma_f32_16x16x32_bf16(afrag3, bu.s, cinit3, 0, 0, 0);
        const float4v a4 = __builtin_amdgcn_mfma_f32_16x16x32_bf16(afrag4, bu.s, cinit4, 0, 0, 0);
        const float4v a5 = __builtin_amdgcn_mfma_f32_16x16x32_bf16(afrag5, bu.s, cinit5, 0, 0, 0);

        #pragma unroll
        for (int i = 0; i < 8; ++i) {
            const int q = i & 3;
            const float ar = (i < 4) ? a0[q] : a1[q];   // -L2E*(hh_r + b_hh_r + b_ih_r)
            const float az = (i < 4) ? a2[q] : a3[q];
            const float an = (i < 4) ? a4[q] : a5[q];   // 2L2E*(hh_n + b_hh_n)
            const float r = frcp(1.0f + fexp2(fmaf(xv, wr[i], ar)));
            const float z = frcp(1.0f + fexp2(fmaf(xv, wz[i], az)));
            const float y = fmaf(r, an, fmaf(xv, wn[i], bn[i]));
            const float n = fmaf(-2.0f, frcp(1.0f + fexp2(y)), 1.0f);  // tanh
            h[i] = fmaf(z, h[i] - n, n);                // (1-z)*n + z*h
        }
    }

    float* __restrict__ o = pre + (size_t)b * (FPn * Hdim) + f * Hdim + 8 * S;
    #pragma unroll
    for (int i = 0; i < 8; ++i) o[i] = h[i];
}

// ---------- epilogue: 1 wave per b.  lane = (h = l&31, f-halfset = l>>5) --------
__global__ __launch_bounds__(64)
void post_kernel(const float* __restrict__ pre,     // [B,18,32] (f<17 valid)
                 const float* __restrict__ statics, // [B,4]
                 const float* __restrict__ demoW,   // [32,4]
                 const float* __restrict__ demob,   // [32]
                 const float* __restrict__ lnw,     // [18,32]
                 const float* __restrict__ lnb,     // [18,32]
                 const float* __restrict__ protos,  // [8,576]
                 const float* __restrict__ pnorm,   // [8]
                 const float* __restrict__ Wq,      // [32,8]
                 const float* __restrict__ bq,      // [32]
                 const float* __restrict__ Wk,      // [8,18]
                 const float* __restrict__ bk,      // [8]
                 const float* __restrict__ Wv,      // [8,18]
                 const float* __restrict__ bv,      // [8]
                 const float* __restrict__ outW,    // [32]
                 const float* __restrict__ outb,    // [1]
                 float* __restrict__ out_logits,    // [B]
                 float* __restrict__ out_dist,      // [B,8]
                 float* __restrict__ out_ht)        // [B,18,32]
{
    const int b     = blockIdx.x;
    const int l     = threadIdx.x;
    const int hl    = l & 31;
    const int fbase = (l >> 5) * 9;

    float v[9];
    #pragma unroll
    for (int j = 0; j < 9; ++j) {
        const int fj = fbase + j;
        if (fj == 17) {
            float acc = demob[hl];
            #pragma unroll
            for (int d = 0; d < 4; ++d)
                acc = fmaf(statics[b * 4 + d], demoW[hl * 4 + d], acc);
            v[j] = acc;
        } else {
            v[j] = pre[(size_t)b * 576 + fj * 32 + hl];
        }
    }

    float s = 0.0f, ss = 0.0f;
    #pragma unroll
    for (int j = 0; j < 9; ++j) { s += v[j]; ss = fmaf(v[j], v[j], ss); }
    #pragma unroll
    for (int m = 32; m; m >>= 1) { s += __shfl_xor(s, m); ss += __shfl_xor(ss, m); }
    const float mu  = s * (1.0f / 576.0f);
    const float var = ss * (1.0f / 576.0f) - mu * mu;
    const float rs  = frsq(var + 1e-5f);

    float nrm = 0.0f;
    #pragma unroll
    for (int j = 0; j < 9; ++j) {
        const int fj = fbase + j;
        float y = fmaf((v[j] - mu) * rs, lnw[fj * 32 + hl], lnb[fj * 32 + hl]);
        v[j] = y;
        out_ht[(size_t)b * 576 + fj * 32 + hl] = y;
        nrm = fmaf(y, y, nrm);
    }
    #pragma unroll
    for (int m = 32; m; m >>= 1) nrm += __shfl_xor(nrm, m);
    nrm = sqrtf(nrm);

    float dist[8];
    #pragma unroll
    for (int p = 0; p < Pnum; ++p) {
        float d = 0.0f;
        #pragma unroll
        for (int j = 0; j < 9; ++j)
            d = fmaf(v[j], protos[p * 576 + (fbase + j) * 32 + hl], d);
        #pragma unroll
        for (int m = 32; m; m >>= 1) d += __shfl_xor(d, m);
        dist[p] = d / fmaxf(nrm * pnorm[p], 1e-8f);
    }
    if (l == 0) {
        #pragma unroll
        for (int p = 0; p < Pnum; ++p) out_dist[(size_t)b * Pnum + p] = dist[p];
    }

    float q = bq[hl];
    #pragma unroll
    for (int p = 0; p < Pnum; ++p) q = fmaf(dist[p], Wq[hl * 8 + p], q);
    float Sq = q;
    #pragma unroll
    for (int m = 16; m; m >>= 1) Sq += __shfl_xor(Sq, m);

    float sf[9], so[9];
    #pragma unroll
    for (int j = 0; j < 9; ++j) {
        float t = v[j] * q;
        #pragma unroll
        for (int m = 16; m; m >>= 1) t += __shfl_xor(t, m);
        sf[j] = t;
    }
    #pragma unroll
    for (int j = 0; j < 9; ++j) so[j] = __shfl_xor(sf[j], 32);
    const int obase = 9 - fbase;

    float e[8];
    #pragma unroll
    for (int p = 0; p < Pnum; ++p) {
        float a = bk[p] * Sq;
        #pragma unroll
        for (int j = 0; j < 9; ++j) {
            a = fmaf(sf[j], Wk[p * FPn + fbase + j], a);
            a = fmaf(so[j], Wk[p * FPn + obase + j], a);
        }
        e[p] = a;
    }
    float mx = e[0];
    #pragma unroll
    for (int p = 1; p < Pnum; ++p) mx = fmaxf(mx, e[p]);
    float aw[8], den = 0.0f;
    #pragma unroll
    for (int p = 0; p < Pnum; ++p) { aw[p] = __expf(e[p] - mx); den += aw[p]; }
    const float rden = frcp(den);
    #pragma unroll
    for (int p = 0; p < Pnum; ++p) aw[p] *= rden;

    float cc = 0.0f;
    #pragma unroll
    for (int p = 0; p < Pnum; ++p) cc = fmaf(aw[p], bv[p], cc);
    float vb = 0.0f;
    #pragma unroll
    for (int j = 0; j < 9; ++j) {
        float wv = 0.0f;
        #pragma unroll
        for (int p = 0; p < Pnum; ++p) wv = fmaf(aw[p], Wv[p * FPn + fbase + j], wv);
        vb = fmaf(v[j], wv, vb);
    }
    vb += __shfl_xor(vb, 32);
    vb += cc;

    float lg = vb * outW[hl];
    #pragma unroll
    for (int m = 16; m; m >>= 1) lg += __shfl_xor(lg, m);
    lg = fsigmoid(lg + outb[0]);
    if (l == 0) out_logits[b] = lg;
}

extern "C" void kernel_launch(void* const* d_in, const int* in_sizes, int n_in,
                              void* d_out, int out_size, void* d_ws, size_t ws_size,
                              hipStream_t stream) {
    const float* x      = (const float*)d_in[0];
    const float* statics= (const float*)d_in[1];
    const float* Wih    = (const float*)d_in[2];
    const float* Whh    = (const float*)d_in[3];
    const float* bih    = (const float*)d_in[4];
    const float* bhh    = (const float*)d_in[5];
    const float* demoW  = (const float*)d_in[6];
    const float* demob  = (const float*)d_in[7];
    const float* lnw    = (const float*)d_in[8];
    const float* lnb    = (const float*)d_in[9];
    const float* protos = (const float*)d_in[10];
    const float* Wq     = (const float*)d_in[11];
    const float* bq     = (const float*)d_in[12];
    const float* Wk     = (const float*)d_in[13];
    const float* bk     = (const float*)d_in[14];
    const float* Wv     = (const float*)d_in[15];
    const float* bv     = (const float*)d_in[16];
    const float* outW   = (const float*)d_in[17];
    const float* outb   = (const float*)d_in[18];

    // ws layout: pre[B*576] f32 | pnorm[8] f32 | xT[F,T+1,B] bf16
    float* pre   = (float*)d_ws;
    float* pnorm = pre + (size_t)Bsz * FPn * Hdim;
    unsigned short* xT = (unsigned short*)(pnorm + 8);
    const size_t need = ((size_t)Bsz * FPn * Hdim + 8) * 4
                      + (size_t)Fnum * (Tlen + 1) * Bsz * 2;
    const bool use_xt = (ws_size >= need);

    prep_pnorm_kernel<<<dim3(1), dim3(256), 0, stream>>>(protos, pnorm);

    if (use_xt) {
        xpose_kernel<<<dim3(Bsz / 64, Tlen), dim3(64), 0, stream>>>(x, xT);
        gru_mfma_kernel<1><<<dim3(Bsz / 16, Fnum), dim3(64), 0, stream>>>(
            x, xT, Wih, Whh, bih, bhh, pre);
    } else {
        gru_mfma_kernel<0><<<dim3(Bsz / 16, Fnum), dim3(64), 0, stream>>>(
            x, xT, Wih, Whh, bih, bhh, pre);
    }

    float* out_logits = (float*)d_out;
    float* out_dist   = out_logits + Bsz;
    float* out_ht     = out_dist + (size_t)Bsz * Pnum;

    post_kernel<<<dim3(Bsz), dim3(64), 0, stream>>>(
        pre, statics, demoW, demob, lnw, lnb, protos, pnorm,
        Wq, bq, Wk, bk, Wv, bv, outW, outb,
        out_logits, out_dist, out_ht);
}